// Round 3
// baseline (1887.123 us; speedup 1.0000x reference)
//
#include <hip/hip_runtime.h>

#define NN 50000
#define NE 800000
#define NG 128
#define NL 3

typedef __attribute__((ext_vector_type(8))) short short8;
typedef __attribute__((ext_vector_type(4))) float f32x4;
typedef __attribute__((ext_vector_type(4))) int i32x4;

union FragU { i32x4 i; short8 s; };

__device__ __forceinline__ float silu_f(float x) { return x / (1.f + __expf(-x)); }
__device__ __forceinline__ float rdl(float v, int l) {
  return __int_as_float(__builtin_amdgcn_readlane(__float_as_int(v), l));
}
__device__ __forceinline__ float wave_sum(float v) {
#pragma unroll
  for (int m = 1; m < 64; m <<= 1) v += __shfl_xor(v, m, 64);
  return v;
}

__device__ __forceinline__ unsigned f2u(float x) { return __float_as_uint(x); }
__device__ __forceinline__ float hi_part(float x) {
  return __uint_as_float(f2u(x) & 0xffff0000u);
}
// pack two fp32 -> (bf16,bf16) dword via truncation; e0 in low half
__device__ __forceinline__ unsigned pk_hi(float e0, float e1) {
  return __builtin_amdgcn_perm(f2u(e1), f2u(e0), 0x07060302u);
}
// fp32 -> one dword: hi-bf16 bits in high half, lo-bf16 (residual) in low half
__device__ __forceinline__ unsigned pk_hilo(float x) {
  unsigned h = f2u(x) & 0xffff0000u;
  float r = x - __uint_as_float(h);
  return h | (f2u(r) >> 16);
}

__device__ __forceinline__ f32x4 mfma16(i32x4 a, i32x4 b, f32x4 c) {
  FragU ua, ub; ua.i = a; ub.i = b;
  return __builtin_amdgcn_mfma_f32_16x16x32_bf16(ua.s, ub.s, c, 0, 0, 0);
}

// split 8 fp32 into hi/lo bf16x8 fragments (A-frag element order: k ascending)
__device__ __forceinline__ void split8(const float* x, i32x4& fh, i32x4& fl) {
#pragma unroll
  for (int i = 0; i < 4; ++i) {
    const float a = x[2 * i], b = x[2 * i + 1];
    fh[i] = (int)pk_hi(a, b);
    fl[i] = (int)pk_hi(a - hi_part(a), b - hi_part(b));
  }
}

// build B-frag (hi/lo) for W[k][n] tile: rows k0..k0+31, cols c0..c0+15 (ld=64)
__device__ __forceinline__ void wfrag(const float* __restrict__ W, int nrows, int k0,
                                      int c0, int lane, i32x4& fh, i32x4& fl) {
  const int kb = k0 + ((lane >> 4) << 3);
  const int n = c0 + (lane & 15);
  float x[8];
#pragma unroll
  for (int j = 0; j < 8; ++j) {
    const int k = kb + j;
    x[j] = (k < nrows) ? W[k * 64 + n] : 0.f;
  }
  split8(x, fh, fl);
}

// unpack 8 (hi|lo)-packed dwords into hi/lo A-frags
__device__ __forceinline__ void unpack8(const unsigned* d, i32x4& fh, i32x4& fl) {
#pragma unroll
  for (int i = 0; i < 4; ++i) {
    fh[i] = (int)__builtin_amdgcn_perm(d[2 * i + 1], d[2 * i], 0x07060302u);
    fl[i] = (int)__builtin_amdgcn_perm(d[2 * i + 1], d[2 * i], 0x05040100u);
  }
}

__device__ __forceinline__ void unpack8v(uint4 a, uint4 b, i32x4& fh, i32x4& fl) {
  unsigned d[8] = {a.x, a.y, a.z, a.w, b.x, b.y, b.z, b.w};
  unpack8(d, fh, fl);
}

// ---------------- init / small kernels ----------------
__global__ __launch_bounds__(256) void k_init_h(const int* __restrict__ nt,
                                                const float* __restrict__ emb,
                                                float* __restrict__ h,
                                                unsigned* __restrict__ hp) {
  int idx = blockIdx.x * 256 + threadIdx.x;
  if (idx < NN * 64) {
    const float v = emb[nt[idx >> 6] * 64 + (idx & 63)];
    h[idx] = v;
    hp[idx] = pk_hilo(v);
  }
}

__global__ __launch_bounds__(256) void k_prep(const float* __restrict__ pos_in,
                                              float* __restrict__ pos,
                                              float* __restrict__ deg,
                                              float* __restrict__ g,
                                              float* __restrict__ gcnt) {
  int idx = blockIdx.x * 256 + threadIdx.x;
  if (idx < NN * 3) pos[idx] = pos_in[idx];
  if (idx < NN) deg[idx] = 0.f;
  if (idx < NG * 64) g[idx] = 0.f;
  if (idx < NG) gcnt[idx] = 0.f;
}

__global__ __launch_bounds__(256) void k_hist(const int* __restrict__ ei,
                                              float* __restrict__ deg) {
  int e = blockIdx.x * 256 + threadIdx.x;
  if (e < NE) atomicAdd(&deg[ei[NE + e]], 1.f);
}

__global__ __launch_bounds__(256) void k_cnt(const int* __restrict__ batch,
                                             float* __restrict__ deg,
                                             float* __restrict__ gcnt) {
  int i = blockIdx.x * 256 + threadIdx.x;
  if (i < NN) {
    deg[i] = fmaxf(deg[i], 1.f);
    atomicAdd(&gcnt[batch[i]], 1.f);
  }
}

__global__ __launch_bounds__(256) void k_zero(float* __restrict__ agg,
                                              float* __restrict__ posd) {
  int idx = blockIdx.x * 256 + threadIdx.x;
  if (idx < NN * 64) agg[idx] = 0.f;
  else if (idx < NN * 64 + NN * 3) posd[idx - NN * 64] = 0.f;
}

__global__ __launch_bounds__(256) void k_pos(float* __restrict__ pos,
                                             const float* __restrict__ posd,
                                             const float* __restrict__ deg) {
  int idx = blockIdx.x * 256 + threadIdx.x;
  if (idx < NN * 3) pos[idx] += posd[idx] / deg[idx / 3];
}

__global__ __launch_bounds__(256) void k_pool(const float* __restrict__ h,
                                              const int* __restrict__ batch,
                                              float* __restrict__ g) {
  int idx = blockIdx.x * 256 + threadIdx.x;
  if (idx < NN * 64) atomicAdd(&g[batch[idx >> 6] * 64 + (idx & 63)], h[idx]);
}

// ---------------- edge message kernel (split-bf16 MFMA, 32 edges/iter) ------
// block = 4 waves; 32 edges per iteration as 2 independent 16-edge subtiles
// (2x MFMA/gather ILP, 3 syncs per 32 edges). Wave w owns output cols
// [16w,16w+16). Weights resident in VGPRs. h pre-packed (hi|lo dword) as hp.
__global__ __launch_bounds__(256, 3) void k_edge(
    const unsigned* __restrict__ hp, const float* __restrict__ pos,
    const int* __restrict__ ei, const float* __restrict__ eattr,
    const float* __restrict__ W1, const float* __restrict__ B1,
    const float* __restrict__ W2, const float* __restrict__ B2,
    const float* __restrict__ C1, const float* __restrict__ CB1,
    const float* __restrict__ C2, const float* __restrict__ CB2,
    float* __restrict__ agg, float* __restrict__ posd) {
  __shared__ unsigned buf1[32 * 68];
  __shared__ unsigned buf2[32 * 68];
  __shared__ float cpart[2][4][16];

  const int lane = threadIdx.x & 63;
  const int w = threadIdx.x >> 6;
  const int m = lane & 15;
  const int quad = lane >> 4;
  const int col = 16 * w + m;

  i32x4 w1h[5], w1l[5], w2h[2], w2l[2], c1h[2], c1l[2];
#pragma unroll
  for (int s = 0; s < 5; ++s) wfrag(W1, 133, 32 * s, 16 * w, lane, w1h[s], w1l[s]);
#pragma unroll
  for (int s = 0; s < 2; ++s) wfrag(W2, 64, 32 * s, 16 * w, lane, w2h[s], w2l[s]);
#pragma unroll
  for (int s = 0; s < 2; ++s) wfrag(C1, 64, 32 * s, 16 * w, lane, c1h[s], c1l[s]);

  const float eb1v = B1[col], eb2v = B2[col], cb1v = CB1[col];
  const float cw2v = C2[col], cb2v = CB2[0];

  const int ngroups = NE / 32;
  for (int g = blockIdx.x; g < ngroups; g += gridDim.x) {
    const int e0 = g * 32;
    int esrc[2], edst[2];
#pragma unroll
    for (int t = 0; t < 2; ++t) {
      esrc[t] = ei[e0 + t * 16 + m];
      edst[t] = ei[NE + e0 + t * 16 + m];
    }
    float d2v[2], ea0[2], ea1[2], ea2[2], ea3[2], rx[2], ry[2], rz[2];
#pragma unroll
    for (int t = 0; t < 2; ++t) {
      d2v[t] = ea0[t] = ea1[t] = ea2[t] = ea3[t] = 0.f;
      rx[t] = ry[t] = rz[t] = 0.f;
      if (lane < 16) {
        const int e = e0 + t * 16 + lane;
        const int s_ = ei[e], d_ = ei[NE + e];
        rx[t] = pos[d_ * 3 + 0] - pos[s_ * 3 + 0];
        ry[t] = pos[d_ * 3 + 1] - pos[s_ * 3 + 1];
        rz[t] = pos[d_ * 3 + 2] - pos[s_ * 3 + 2];
        d2v[t] = rx[t] * rx[t] + ry[t] * ry[t] + rz[t] * rz[t];
        const float4 ea = *(const float4*)(eattr + 4 * e);
        ea0[t] = ea.x; ea1[t] = ea.y; ea2[t] = ea.z; ea3[t] = ea.w;
      }
    }

    // ---- GEMV1: m_in[32 x 160] @ W1[160 x 64] (this wave: 16 cols) ----
    f32x4 accA[2], accB[2];
#pragma unroll
    for (int t = 0; t < 2; ++t) {
      accA[t] = {eb1v, eb1v, eb1v, eb1v};
      accB[t] = {0.f, 0.f, 0.f, 0.f};
    }
#pragma unroll
    for (int s = 0; s < 4; ++s)
#pragma unroll
      for (int t = 0; t < 2; ++t) {
        const uint4* p = (const uint4*)(hp + (size_t)(s < 2 ? edst[t] : esrc[t]) * 64 +
                                        (s & 1) * 32 + quad * 8);
        i32x4 ah, al;
        unpack8v(p[0], p[1], ah, al);
        accA[t] = mfma16(ah, w1h[s], accA[t]);
        accB[t] = mfma16(ah, w1l[s], accB[t]);
        accB[t] = mfma16(al, w1h[s], accB[t]);
      }
#pragma unroll
    for (int t = 0; t < 2; ++t) {  // tail: cols 128..159 = [d2, ea0..3, 0..]
      float x[8] = {d2v[t], ea0[t], ea1[t], ea2[t], ea3[t], 0.f, 0.f, 0.f};
      i32x4 ah, al;
      split8(x, ah, al);
      accA[t] = mfma16(ah, w1h[4], accA[t]);
      accB[t] = mfma16(ah, w1l[4], accB[t]);
      accB[t] = mfma16(al, w1h[4], accB[t]);
    }
#pragma unroll
    for (int t = 0; t < 2; ++t)
#pragma unroll
      for (int r = 0; r < 4; ++r)
        buf1[(t * 16 + quad * 4 + r) * 68 + col] = pk_hilo(silu_f(accA[t][r] + accB[t][r]));
    __syncthreads();

    // ---- GEMV2: m1[32 x 64] @ W2[64 x 64] ----
    f32x4 acc2[2];
#pragma unroll
    for (int t = 0; t < 2; ++t) acc2[t] = {eb2v, eb2v, eb2v, eb2v};
#pragma unroll
    for (int s = 0; s < 2; ++s)
#pragma unroll
      for (int t = 0; t < 2; ++t) {
        const uint4* p = (const uint4*)&buf1[(t * 16 + m) * 68 + 32 * s + quad * 8];
        i32x4 ah, al;
        unpack8v(p[0], p[1], ah, al);
        acc2[t] = mfma16(ah, w2h[s], acc2[t]);
        acc2[t] = mfma16(ah, w2l[s], acc2[t]);
        acc2[t] = mfma16(al, w2h[s], acc2[t]);
      }
    float mmv[2][4];
#pragma unroll
    for (int t = 0; t < 2; ++t)
#pragma unroll
      for (int r = 0; r < 4; ++r) {
        mmv[t][r] = silu_f(acc2[t][r]);
        buf2[(t * 16 + quad * 4 + r) * 68 + col] = pk_hilo(mmv[t][r]);
        const int rd = __shfl(edst[t], quad * 4 + r, 16);
        atomicAdd(&agg[(size_t)rd * 64 + col], mmv[t][r]);
      }
    __syncthreads();

    // ---- coord MLP: a3 = mm @ C1 + cb1; c = sum(silu(a3)*cw2) + cb2 ----
    f32x4 acc3[2];
#pragma unroll
    for (int t = 0; t < 2; ++t) acc3[t] = {cb1v, cb1v, cb1v, cb1v};
#pragma unroll
    for (int s = 0; s < 2; ++s)
#pragma unroll
      for (int t = 0; t < 2; ++t) {
        const uint4* p = (const uint4*)&buf2[(t * 16 + m) * 68 + 32 * s + quad * 8];
        i32x4 ah, al;
        unpack8v(p[0], p[1], ah, al);
        acc3[t] = mfma16(ah, c1h[s], acc3[t]);
        acc3[t] = mfma16(ah, c1l[s], acc3[t]);
        acc3[t] = mfma16(al, c1h[s], acc3[t]);
      }
    float tr[2][4];
#pragma unroll
    for (int t = 0; t < 2; ++t)
#pragma unroll
      for (int r = 0; r < 4; ++r) tr[t][r] = silu_f(acc3[t][r]) * cw2v;
#pragma unroll
    for (int mask = 1; mask < 16; mask <<= 1)
#pragma unroll
      for (int t = 0; t < 2; ++t)
#pragma unroll
        for (int r = 0; r < 4; ++r) tr[t][r] += __shfl_xor(tr[t][r], mask, 64);
    if (m == 0)
#pragma unroll
      for (int t = 0; t < 2; ++t)
#pragma unroll
        for (int r = 0; r < 4; ++r) cpart[t][w][quad * 4 + r] = tr[t][r];
    __syncthreads();

    if (w == 0 && lane < 16) {
#pragma unroll
      for (int t = 0; t < 2; ++t) {
        const float cv = cpart[t][0][lane] + cpart[t][1][lane] + cpart[t][2][lane] +
                         cpart[t][3][lane] + cb2v;
        const int d_ = ei[NE + e0 + t * 16 + lane];
        atomicAdd(&posd[d_ * 3 + 0], rx[t] * cv);
        atomicAdd(&posd[d_ * 3 + 1], ry[t] * cv);
        atomicAdd(&posd[d_ * 3 + 2], rz[t] * cv);
      }
    }
  }
}

// ---------------- node update kernel ----------------
__global__ __launch_bounds__(256) void k_node(
    float* __restrict__ h, unsigned* __restrict__ hp, const float* __restrict__ agg,
    const float* __restrict__ W1, const float* __restrict__ B1,
    const float* __restrict__ W2, const float* __restrict__ B2) {
  __shared__ float sW1[128 * 64];
  __shared__ float sW2[64 * 64];
  for (int i = threadIdx.x; i < 128 * 64; i += 256) sW1[i] = W1[i];
  for (int i = threadIdx.x; i < 64 * 64; i += 256) sW2[i] = W2[i];
  __syncthreads();
  const int lane = threadIdx.x & 63;
  const float nb1 = B1[lane], nb2 = B2[lane];
  const int wid = (blockIdx.x * 256 + threadIdx.x) >> 6;
  const int nw = (gridDim.x * 256) >> 6;
  for (int n = wid; n < NN; n += nw) {
    const float hj = h[n * 64 + lane];
    const float aj = agg[n * 64 + lane];
    float a1 = nb1;
#pragma unroll
    for (int k = 0; k < 64; ++k) a1 += rdl(hj, k) * sW1[k * 64 + lane];
#pragma unroll
    for (int k = 0; k < 64; ++k) a1 += rdl(aj, k) * sW1[(64 + k) * 64 + lane];
    const float u = silu_f(a1);
    float a2 = nb2;
#pragma unroll
    for (int k = 0; k < 64; ++k) a2 += rdl(u, k) * sW2[k * 64 + lane];
    const float hn = hj + a2;
    h[n * 64 + lane] = hn;
    hp[n * 64 + lane] = pk_hilo(hn);
  }
}

// ---------------- pooled head: q-circuit + MLP ----------------
__global__ __launch_bounds__(256) void k_final(
    const float* __restrict__ g, const float* __restrict__ gcnt,
    const float* __restrict__ prew, const float* __restrict__ preb,
    const float* __restrict__ qw, const float* __restrict__ pw1,
    const float* __restrict__ pb1, const float* __restrict__ pw2,
    const float* __restrict__ pb2, float* __restrict__ out) {
  const int lane = threadIdx.x & 63;
  const int gid = (blockIdx.x * 256 + threadIdx.x) >> 6;
  if (gid >= NG) return;
  const float cnt = fmaxf(gcnt[gid], 1.f);
  const float gv = g[gid * 64 + lane] / cnt;
  float qin[4];
#pragma unroll
  for (int q = 0; q < 4; ++q)
    qin[q] = wave_sum(gv * prew[lane * 4 + q]) + preb[q];
  float sr[16], si[16];
#pragma unroll
  for (int i = 0; i < 16; ++i) { sr[i] = 0.f; si[i] = 0.f; }
  sr[0] = 1.f;
#pragma unroll
  for (int q = 0; q < 4; ++q) {  // RX(qin[q])
    const int mask = 8 >> q;
    float s, c;
    __sincosf(qin[q] * 0.5f, &s, &c);
#pragma unroll
    for (int i = 0; i < 16; ++i)
      if (!(i & mask)) {
        const int j = i | mask;
        const float ar = sr[i], ai = si[i], br = sr[j], bi = si[j];
        sr[i] = c * ar + s * bi; si[i] = c * ai - s * br;
        sr[j] = c * br + s * ai; si[j] = c * bi - s * ar;
      }
  }
#pragma unroll
  for (int l = 0; l < 2; ++l) {
#pragma unroll
    for (int q = 0; q < 4; ++q) {  // RY(qw[l][q])
      const int mask = 8 >> q;
      float s, c;
      __sincosf(qw[l * 4 + q] * 0.5f, &s, &c);
#pragma unroll
      for (int i = 0; i < 16; ++i)
        if (!(i & mask)) {
          const int j = i | mask;
          const float ar = sr[i], ai = si[i], br = sr[j], bi = si[j];
          sr[i] = c * ar - s * br; si[i] = c * ai - s * bi;
          sr[j] = s * ar + c * br; si[j] = s * ai + c * bi;
        }
    }
#pragma unroll
    for (int q = 0; q < 4; ++q) {  // CNOT q -> (q+1)%4
      const int mc = 8 >> q;
      const int mt = 8 >> ((q + 1) & 3);
#pragma unroll
      for (int i = 0; i < 16; ++i)
        if ((i & mc) && !(i & mt)) {
          const int j = i | mt;
          float t = sr[i]; sr[i] = sr[j]; sr[j] = t;
          t = si[i]; si[i] = si[j]; si[j] = t;
        }
    }
  }
  float qo[4] = {0.f, 0.f, 0.f, 0.f};
#pragma unroll
  for (int i = 0; i < 16; ++i) {
    const float p = sr[i] * sr[i] + si[i] * si[i];
#pragma unroll
    for (int q = 0; q < 4; ++q) qo[q] += ((i >> (3 - q)) & 1) ? -p : p;
  }
  float t = pb1[lane];
#pragma unroll
  for (int q = 0; q < 4; ++q) t += qo[q] * pw1[q * 64 + lane];
  const float r = wave_sum(silu_f(t) * pw2[lane]);
  if (lane == 0) out[gid] = r + pb2[0];
}

extern "C" void kernel_launch(void* const* d_in, const int* in_sizes, int n_in,
                              void* d_out, int out_size, void* d_ws, size_t ws_size,
                              hipStream_t stream) {
  (void)in_sizes; (void)n_in; (void)out_size; (void)ws_size;
  const int*   nt    = (const int*)d_in[0];
  const float* pos0  = (const float*)d_in[1];
  const int*   ei    = (const int*)d_in[2];
  const float* eattr = (const float*)d_in[3];
  const int*   batch = (const int*)d_in[4];
  const float* emb   = (const float*)d_in[5];
  const float* ew1   = (const float*)d_in[6];
  const float* eb1   = (const float*)d_in[7];
  const float* ew2   = (const float*)d_in[8];
  const float* eb2   = (const float*)d_in[9];
  const float* cw1   = (const float*)d_in[10];
  const float* cb1   = (const float*)d_in[11];
  const float* cw2   = (const float*)d_in[12];
  const float* cb2   = (const float*)d_in[13];
  const float* nw1   = (const float*)d_in[14];
  const float* nb1   = (const float*)d_in[15];
  const float* nw2   = (const float*)d_in[16];
  const float* nb2   = (const float*)d_in[17];
  const float* prew  = (const float*)d_in[18];
  const float* preb  = (const float*)d_in[19];
  const float* qw    = (const float*)d_in[20];
  const float* pw1   = (const float*)d_in[21];
  const float* pb1   = (const float*)d_in[22];
  const float* pw2   = (const float*)d_in[23];
  const float* pb2   = (const float*)d_in[24];
  float* out = (float*)d_out;

  float* ws   = (float*)d_ws;
  float* h    = ws;               // NN*64
  float* pos  = h + NN * 64;      // NN*3
  float* posd = pos + NN * 3;     // NN*3
  float* agg  = posd + NN * 3;    // NN*64
  float* deg  = agg + NN * 64;    // NN
  float* g    = deg + NN;         // NG*64
  float* gcnt = g + NG * 64;      // NG
  unsigned* hpp = (unsigned*)(gcnt + NG);  // NN*64 packed hi|lo

  k_init_h<<<(NN * 64 + 255) / 256, 256, 0, stream>>>(nt, emb, h, hpp);
  k_prep<<<(NN * 3 + 255) / 256, 256, 0, stream>>>(pos0, pos, deg, g, gcnt);
  k_hist<<<(NE + 255) / 256, 256, 0, stream>>>(ei, deg);
  k_cnt<<<(NN + 255) / 256, 256, 0, stream>>>(batch, deg, gcnt);
  for (int l = 0; l < NL; ++l) {
    k_zero<<<(NN * 67 + 255) / 256, 256, 0, stream>>>(agg, posd);
    k_edge<<<768, 256, 0, stream>>>(hpp, pos, ei, eattr,
        ew1 + l * 133 * 64, eb1 + l * 64, ew2 + l * 64 * 64, eb2 + l * 64,
        cw1 + l * 64 * 64, cb1 + l * 64, cw2 + l * 64, cb2 + l, agg, posd);
    k_pos<<<(NN * 3 + 255) / 256, 256, 0, stream>>>(pos, posd, deg);
    k_node<<<512, 256, 0, stream>>>(h, hpp, agg, nw1 + l * 128 * 64, nb1 + l * 64,
                                    nw2 + l * 64 * 64, nb2 + l * 64);
  }
  k_pool<<<(NN * 64 + 255) / 256, 256, 0, stream>>>(h, batch, g);
  k_final<<<(NG * 64 + 255) / 256, 256, 0, stream>>>(g, gcnt, prew, preb, qw,
                                                     pw1, pb1, pw2, pb2, out);
}